// Round 1
// 3529.431 us; speedup vs baseline: 4.5396x; 4.5396x over previous
//
#include <hip/hip_runtime.h>

typedef __bf16 bf16_t;
typedef __bf16 bf16x8 __attribute__((ext_vector_type(8)));
typedef __bf16 bf16x4 __attribute__((ext_vector_type(4)));
typedef float floatx4 __attribute__((ext_vector_type(4)));
typedef unsigned long long u64;

#define VOCAB 32000
#define EMB   512
#define HID   1024
#define LAT   128
#define BATCH 32
#define SEQ   128

// ---------------------------------------------------------------------------
// zero barrier counters + h parity-0 buffer
__global__ void zero_init_kernel(int* __restrict__ bars, int nbar, bf16_t* __restrict__ hbuf0) {
    int i = blockIdx.x * blockDim.x + threadIdx.x;
    if (i < nbar) bars[i] = 0;
    unsigned int* hz = (unsigned int*)hbuf0;   // 32*1024 bf16 = 16384 uints
    if (i < 16384) hz[i] = 0u;
}

// counts -> last_idx
__global__ void counts_kernel(const int* __restrict__ tok, int* __restrict__ last_idx) {
    int b = threadIdx.x;
    if (b < BATCH) {
        int cnt = 0;
        for (int t = 0; t < SEQ; ++t) cnt += (tok[b * SEQ + t] != 0);
        int li = cnt - 1;
        if (li < 0) li = 0;
        last_idx[b] = li;
    }
}

// fp32 -> bf16 cast (n multiple of 4)
__global__ void cast_bf16_kernel(const float* __restrict__ src, bf16_t* __restrict__ dst, int n) {
    int i = (blockIdx.x * blockDim.x + threadIdx.x) * 4;
    if (i < n) {
        floatx4 v = *(const floatx4*)(src + i);
        bf16x4 o;
        o[0] = (bf16_t)v[0]; o[1] = (bf16_t)v[1]; o[2] = (bf16_t)v[2]; o[3] = (bf16_t)v[3];
        *(bf16x4*)(dst + i) = o;
    }
}

// gather embedding rows -> xe[(t*32+b)][512] bf16; rows with t>=Tvalid zeroed
__global__ void gather_kernel(const int* __restrict__ tok, const float* __restrict__ emb,
                              bf16_t* __restrict__ xe, int Tvalid, int toff) {
    int m = blockIdx.x;            // 0..4095
    int t = m >> 5, b = m & 31;
    bf16_t* dst = xe + (size_t)m * EMB;
    if (t < Tvalid) {
        int tk = tok[b * SEQ + t + toff];
        const float* src = emb + (size_t)tk * EMB;
        for (int i = threadIdx.x; i < EMB; i += blockDim.x) dst[i] = (bf16_t)src[i];
    } else {
        for (int i = threadIdx.x; i < EMB; i += blockDim.x) dst[i] = (bf16_t)0.f;
    }
}

// ---------------------------------------------------------------------------
// C[m][n] = sum_k A[m][k]*B[n][k] + bias1[n] + bias2[n]   (both row-major, bf16)
// 128x128 tile, BK=32, 4 waves in 2x2, 16x16x32 MFMA, global_load_lds width 16.
__global__ __launch_bounds__(256, 1) void gemm_bt(
    const bf16_t* __restrict__ A, const bf16_t* __restrict__ B,
    float* __restrict__ C, const float* __restrict__ bias1, const float* __restrict__ bias2,
    int M, int N, int K, int Mvalid)
{
    __shared__ bf16_t As[128 * 32];
    __shared__ bf16_t Bs[128 * 32];
    const int tid = threadIdx.x;
    const int lane = tid & 63;
    const int wv = tid >> 6;
    const int wm = wv & 1, wn = wv >> 1;
    const int l16 = lane & 15, kq = lane >> 4;
    const int m0 = blockIdx.y * 128;
    const int n0 = blockIdx.x * 128;

    floatx4 acc[4][4];
#pragma unroll
    for (int i = 0; i < 4; ++i)
#pragma unroll
        for (int j = 0; j < 4; ++j) acc[i][j] = (floatx4){0.f, 0.f, 0.f, 0.f};

    for (int k0 = 0; k0 < K; k0 += 32) {
        __syncthreads();
#pragma unroll
        for (int ch = 0; ch < 2; ++ch) {
            int e = (ch * 256 + tid) * 8;     // bf16 elements
            int row = e >> 5, kc = e & 31;
            __builtin_amdgcn_global_load_lds(
                (const __attribute__((address_space(1))) void*)(A + (size_t)(m0 + row) * K + k0 + kc),
                (__attribute__((address_space(3))) void*)(As + e), 16, 0, 0);
            __builtin_amdgcn_global_load_lds(
                (const __attribute__((address_space(1))) void*)(B + (size_t)(n0 + row) * K + k0 + kc),
                (__attribute__((address_space(3))) void*)(Bs + e), 16, 0, 0);
        }
        __syncthreads();

        bf16x8 af[4], bfv[4];
#pragma unroll
        for (int i = 0; i < 4; ++i) {
            af[i] = *(const bf16x8*)(As + (wm * 64 + i * 16 + l16) * 32 + kq * 8);
            bfv[i] = *(const bf16x8*)(Bs + (wn * 64 + i * 16 + l16) * 32 + kq * 8);
        }
#pragma unroll
        for (int i = 0; i < 4; ++i)
#pragma unroll
            for (int j = 0; j < 4; ++j)
                acc[i][j] = __builtin_amdgcn_mfma_f32_16x16x32_bf16(af[i], bfv[j], acc[i][j], 0, 0, 0);
    }

#pragma unroll
    for (int i = 0; i < 4; ++i) {
#pragma unroll
        for (int j = 0; j < 4; ++j) {
            int col = n0 + wn * 64 + j * 16 + l16;
            int rowb = m0 + wm * 64 + i * 16 + kq * 4;
            float bs = 0.f;
            if (bias1) bs += bias1[col];
            if (bias2) bs += bias2[col];
#pragma unroll
            for (int r = 0; r < 4; ++r) {
                int row = rowb + r;
                if (row < Mvalid) C[(size_t)row * N + col] = acc[i][j][r] + bs;
            }
        }
    }
}

// ---------------------------------------------------------------------------
// Persistent LSTM scan. grid = 256 wgs (1/CU, co-resident), block = 256.
// wg owns 4 hidden units j0..j0+3 -> 16 gate columns (i,f,g,o interleaved).
// Whh slice in LDS bf16 (padded rows). h double-buffered bf16 in global.
//
// Cross-wg h exchange uses TARGETED coherence instead of __threadfence():
//  - h stores/loads are relaxed agent-scope atomics (sc0 sc1: straight to the
//    device coherence point, bypassing the non-coherent per-XCD L1/L2) so NO
//    cache-wide wbl2/inv is issued per step.
//  - barrier arrive/poll are relaxed atomics; ordering of h-stores before the
//    arrive comes from the s_waitcnt vmcnt(0) implied by __syncthreads().
__global__ __launch_bounds__(256, 1) void lstm_persistent(
    const float* __restrict__ xW,      // [T*32][4096]  x@Wih^T + bih + bhh
    const float* __restrict__ Whh,     // [4096][1024] fp32
    bf16_t* __restrict__ hbuf,         // [2][32][1024] bf16
    int T, int is_dec,
    const int* __restrict__ last_idx,  // enc only
    float* __restrict__ last_h,        // enc only [32][1024]
    bf16_t* __restrict__ hd,           // dec only [4096][1024], row = b*126+t
    int* __restrict__ bar)             // [T] zeroed
{
    __shared__ bf16_t Bs[16][1032];            // 16 gate cols x K=1024 (+8 pad)
    __shared__ float part[4][2][16][16];       // [wave][mtile][row=b%16][col=nl]
    __shared__ __align__(8) bf16_t hstage[32][4];  // wg's h slice staging

    const int tid = threadIdx.x;
    const int lane = tid & 63, wv = tid >> 6;
    const int l16 = lane & 15, kq = lane >> 4;
    const int j0 = blockIdx.x * 4;
    const int nwg = gridDim.x;

    // stage Whh slice: local row nl = g*4+jj  <->  Whh row g*1024 + j0 + jj
    for (int idx = tid; idx < 16 * 1024; idx += 256) {
        int nl = idx >> 10, k = idx & 1023;
        int g = nl >> 2, jj = nl & 3;
        Bs[nl][k] = (bf16_t)Whh[(size_t)(g * 1024 + j0 + jj) * 1024 + k];
    }

    const bool active = tid < 128;
    const int b = tid >> 2, jj = tid & 3;      // valid when active
    float c = 0.f;
    int li = 0;
    if (active && !is_dec) li = last_idx[b];
    __syncthreads();

    for (int t = 0; t < T; ++t) {
        const bf16_t* hcur = hbuf + (size_t)(t & 1) * BATCH * HID;
        bf16_t* hnext = hbuf + (size_t)((t + 1) & 1) * BATCH * HID;

        // prefetch this step's xW values early (plain cached loads, independent
        // of h) so their HBM latency hides under the MFMA phase
        float xv[4];
        if (active) {
            const float* xrow = xW + ((size_t)t * BATCH + b) * 4096;
#pragma unroll
            for (int g = 0; g < 4; ++g) xv[g] = xrow[g * 1024 + j0 + jj];
        }

        floatx4 acc0 = (floatx4){0.f, 0.f, 0.f, 0.f};
        floatx4 acc1 = (floatx4){0.f, 0.f, 0.f, 0.f};
        const int kbase = wv * 256;
#pragma unroll
        for (int ks = 0; ks < 8; ++ks) {
            int k = kbase + ks * 32 + kq * 8;
            u64* p0 = (u64*)(hcur + (size_t)l16 * HID + k);
            u64* p1 = (u64*)(hcur + (size_t)(l16 + 16) * HID + k);
            union { bf16x8 v; u64 u[2]; } ua, ub;
            ua.u[0] = __hip_atomic_load(p0,     __ATOMIC_RELAXED, __HIP_MEMORY_SCOPE_AGENT);
            ua.u[1] = __hip_atomic_load(p0 + 1, __ATOMIC_RELAXED, __HIP_MEMORY_SCOPE_AGENT);
            ub.u[0] = __hip_atomic_load(p1,     __ATOMIC_RELAXED, __HIP_MEMORY_SCOPE_AGENT);
            ub.u[1] = __hip_atomic_load(p1 + 1, __ATOMIC_RELAXED, __HIP_MEMORY_SCOPE_AGENT);
            bf16x8 bb = *(const bf16x8*)(&Bs[l16][k]);
            acc0 = __builtin_amdgcn_mfma_f32_16x16x32_bf16(ua.v, bb, acc0, 0, 0, 0);
            acc1 = __builtin_amdgcn_mfma_f32_16x16x32_bf16(ub.v, bb, acc1, 0, 0, 0);
        }
#pragma unroll
        for (int r = 0; r < 4; ++r) {
            part[wv][0][kq * 4 + r][l16] = acc0[r];
            part[wv][1][kq * 4 + r][l16] = acc1[r];
        }
        __syncthreads();

        if (active) {
            float gv[4];
            const int mt = b >> 4, rr = b & 15;
#pragma unroll
            for (int g = 0; g < 4; ++g) {
                int nl = g * 4 + jj;
                float s = part[0][mt][rr][nl] + part[1][mt][rr][nl]
                        + part[2][mt][rr][nl] + part[3][mt][rr][nl];
                gv[g] = s + xv[g];
            }
            float ig = 1.f / (1.f + expf(-gv[0]));
            float fg = 1.f / (1.f + expf(-gv[1]));
            float gg = tanhf(gv[2]);
            float og = 1.f / (1.f + expf(-gv[3]));
            c = fg * c + ig * gg;
            float hval = og * tanhf(c);
            bf16_t hb = (bf16_t)hval;
            hstage[b][jj] = hb;
            if (!is_dec) {
                if (t == li) last_h[(size_t)b * HID + j0 + jj] = hval;
            } else {
                hd[((size_t)b * 126 + t) * HID + j0 + jj] = hb;
            }
        }
        __syncthreads();                       // hstage complete

        // publish h slice: 32 lanes x 8B coherent (sc0 sc1) stores
        if (tid < 32) {
            u64 val = *(const u64*)(&hstage[tid][0]);
            __hip_atomic_store((u64*)(hnext + (size_t)tid * HID + j0), val,
                               __ATOMIC_RELAXED, __HIP_MEMORY_SCOPE_AGENT);
        }

        if (t < T - 1) {
            __syncthreads();                   // drains vmcnt -> h stores at coherence point
            if (tid == 0) {
                __hip_atomic_fetch_add(&bar[t], 1, __ATOMIC_RELAXED, __HIP_MEMORY_SCOPE_AGENT);
                while (__hip_atomic_load(&bar[t], __ATOMIC_RELAXED, __HIP_MEMORY_SCOPE_AGENT) < nwg)
                    __builtin_amdgcn_s_sleep(2);
            }
            __syncthreads();
        }
    }
}

// ---------------------------------------------------------------------------
// mean / log_var / z / h0. grid = 32 (one per batch), block = 256.
__global__ __launch_bounds__(256, 1) void latent_kernel(
    const float* __restrict__ last_h,
    const float* __restrict__ W_mu, const float* __restrict__ b_mu,
    const float* __restrict__ W_lv, const float* __restrict__ b_lv,
    const float* __restrict__ eps,
    const float* __restrict__ W_l2h, const float* __restrict__ b_l2h,
    float* __restrict__ mean_out, float* __restrict__ lv_out,
    bf16_t* __restrict__ h0buf)   // parity-0 h buffer [32][1024]
{
    __shared__ float ms[LAT], ls[LAT], zs[LAT];
    const int bq = blockIdx.x, tid = threadIdx.x;
    const float* hb = last_h + (size_t)bq * HID;

    {
        int j = tid & 127;
        const float* W = (tid < 128) ? (W_mu + (size_t)j * HID) : (W_lv + (size_t)j * HID);
        float s = 0.f;
        for (int k = 0; k < HID; k += 4)
            s += hb[k] * W[k] + hb[k + 1] * W[k + 1] + hb[k + 2] * W[k + 2] + hb[k + 3] * W[k + 3];
        if (tid < 128) {
            float mv = s + b_mu[j];
            ms[j] = mv;
            mean_out[bq * LAT + j] = mv;
        } else {
            float lv = s + b_lv[j];
            ls[j] = lv;
            lv_out[bq * LAT + j] = lv;
        }
    }
    __syncthreads();
    if (tid < 128) zs[tid] = ms[tid] + eps[bq * LAT + tid] * expf(0.5f * ls[tid]);
    __syncthreads();

    for (int col = tid; col < HID; col += 256) {
        const float* W = W_l2h + (size_t)col * LAT;
        float s = b_l2h[col];
        for (int l = 0; l < LAT; ++l) s += zs[l] * W[l];
        h0buf[(size_t)bq * HID + col] = (bf16_t)s;
    }
}

// ---------------------------------------------------------------------------
extern "C" void kernel_launch(void* const* d_in, const int* in_sizes, int n_in,
                              void* d_out, int out_size, void* d_ws, size_t ws_size,
                              hipStream_t stream) {
    const int*   tok     = (const int*)d_in[0];
    const float* emb_enc = (const float*)d_in[1];
    const float* Wih_e   = (const float*)d_in[2];
    const float* Whh_e   = (const float*)d_in[3];
    const float* bih_e   = (const float*)d_in[4];
    const float* bhh_e   = (const float*)d_in[5];
    const float* W_mu    = (const float*)d_in[6];
    const float* b_mu    = (const float*)d_in[7];
    const float* W_lv    = (const float*)d_in[8];
    const float* b_lv    = (const float*)d_in[9];
    const float* emb_dec = (const float*)d_in[10];
    const float* W_l2h   = (const float*)d_in[11];
    const float* b_l2h   = (const float*)d_in[12];
    const float* Wih_d   = (const float*)d_in[13];
    const float* Whh_d   = (const float*)d_in[14];
    const float* bih_d   = (const float*)d_in[15];
    const float* bhh_d   = (const float*)d_in[16];
    const float* W_out   = (const float*)d_in[17];
    const float* b_out   = (const float*)d_in[18];
    const float* eps     = (const float*)d_in[19];
    float* out = (float*)d_out;

    char* ws = (char*)d_ws;
    size_t off = 0;
    auto alloc = [&](size_t bytes) -> void* {
        void* p = ws + off;
        off += (bytes + 255) & ~(size_t)255;
        return p;
    };
    bf16_t* Wih_e_b = (bf16_t*)alloc((size_t)4096 * 512 * 2);
    bf16_t* Wih_d_b = (bf16_t*)alloc((size_t)4096 * 512 * 2);
    bf16_t* W_out_b = (bf16_t*)alloc((size_t)VOCAB * HID * 2);
    bf16_t* xe      = (bf16_t*)alloc((size_t)4096 * 512 * 2);
    float*  xW      = (float*)alloc((size_t)4096 * 4096 * 4);
    bf16_t* hd      = (bf16_t*)alloc((size_t)4096 * HID * 2);
    bf16_t* hbuf    = (bf16_t*)alloc((size_t)2 * BATCH * HID * 2);
    float*  last_h  = (float*)alloc((size_t)BATCH * HID * 4);
    int*    last_i  = (int*)alloc(256);
    int*    bars    = (int*)alloc(512 * 4);   // [0..255] enc, [256..511] dec

    const size_t logits_off = (size_t)BATCH * 126 * VOCAB;  // 129,024,000
    float* mean_out = out + logits_off;
    float* lv_out   = out + logits_off + BATCH * LAT;

    zero_init_kernel<<<64, 256, 0, stream>>>(bars, 512, hbuf);
    counts_kernel<<<1, 64, 0, stream>>>(tok, last_i);

    { int n = 4096 * 512;
      cast_bf16_kernel<<<(n / 4 + 255) / 256, 256, 0, stream>>>(Wih_e, Wih_e_b, n);
      cast_bf16_kernel<<<(n / 4 + 255) / 256, 256, 0, stream>>>(Wih_d, Wih_d_b, n); }
    { int n = VOCAB * HID;
      cast_bf16_kernel<<<(n / 4 + 255) / 256, 256, 0, stream>>>(W_out, W_out_b, n); }

    // ----- encoder -----
    gather_kernel<<<4096, 256, 0, stream>>>(tok, emb_enc, xe, 128, 0);
    gemm_bt<<<dim3(32, 32), 256, 0, stream>>>(xe, Wih_e_b, xW, bih_e, bhh_e, 4096, 4096, 512, 4096);
    lstm_persistent<<<256, 256, 0, stream>>>(xW, Whh_e, hbuf, 128, 0, last_i, last_h, nullptr, bars);

    // ----- latent -----
    latent_kernel<<<32, 256, 0, stream>>>(last_h, W_mu, b_mu, W_lv, b_lv, eps,
                                          W_l2h, b_l2h, mean_out, lv_out, hbuf);

    // ----- decoder -----
    gather_kernel<<<4096, 256, 0, stream>>>(tok, emb_dec, xe, 126, 1);
    gemm_bt<<<dim3(32, 32), 256, 0, stream>>>(xe, Wih_d_b, xW, bih_d, bhh_d, 4096, 4096, 512, 4096);
    lstm_persistent<<<256, 256, 0, stream>>>(xW, Whh_d, hbuf, 126, 1, nullptr, nullptr, hd, bars + 256);

    // ----- logits -----
    gemm_bt<<<dim3(250, 32), 256, 0, stream>>>(hd, W_out_b, out, b_out, nullptr,
                                               4096, VOCAB, HID, 4032);
}